// Round 4
// baseline (68.041 us; speedup 1.0000x reference)
//
#include <hip/hip_runtime.h>

#define NPTS   8192
#define BATCH  2
#define CH     64

#define IPT    4
#define ITILE  (IPT*256)      // 1024 i's per block
#define JTILE  64             // j's per block
#define NIT    (NPTS/ITILE)   // 8
#define NJT    (NPTS/JTILE)   // 128
#define NTOT   (BATCH*NIT*NJT) // 2048 blocks total
#define NGROUPS  50
#define NBUCKBLK (BATCH*NGROUPS)  // 100 (folded into blocks 0..99)
#define BUCK_CAP 512

// ---------------- Kernel 1: Fsim = W @ l0 + b (SoA + |f|^2), counter reset ----
__global__ __launch_bounds__(256) void fsim_kernel(
    const float* __restrict__ l0, const float* __restrict__ W,
    const float* __restrict__ bias,
    float* __restrict__ fx, float* __restrict__ fy, float* __restrict__ fz,
    float* __restrict__ fw, int* __restrict__ counter)
{
    if (blockIdx.x == 0 && threadIdx.x == 0)
        __hip_atomic_store(counter, 0, __ATOMIC_RELAXED, __HIP_MEMORY_SCOPE_AGENT);

    __shared__ float sW[3 * CH];
    const int tid = threadIdx.x;
    if (tid < 3 * CH) sW[tid] = W[tid];
    __syncthreads();

    const int lane = tid & 63;
    const int wave = tid >> 6;
    const int p    = lane & 15;
    const int cg   = lane >> 4;
    const int pt   = blockIdx.x * 64 + wave * 16 + p;
    const int b    = pt >> 13;
    const int n    = pt & (NPTS - 1);

    const float* base = l0 + (size_t)b * CH * NPTS + n;
    float ax = 0.f, ay = 0.f, az = 0.f;
    #pragma unroll
    for (int k = 0; k < 16; ++k) {
        int c = cg * 16 + k;
        float v = base[(size_t)c * NPTS];
        ax = fmaf(sW[c],        v, ax);
        ay = fmaf(sW[CH + c],   v, ay);
        az = fmaf(sW[2*CH + c], v, az);
    }
    ax += __shfl_down(ax, 32, 64); ay += __shfl_down(ay, 32, 64); az += __shfl_down(az, 32, 64);
    ax += __shfl_down(ax, 16, 64); ay += __shfl_down(ay, 16, 64); az += __shfl_down(az, 16, 64);
    if (cg == 0) {
        float X = ax + bias[0], Y = ay + bias[1], Z = az + bias[2];
        fx[pt] = X; fy[pt] = Y; fz[pt] = Z;
        fw[pt] = fmaf(X, X, fmaf(Y, Y, Z * Z));
    }
}

// inner body: t = 1 + |fi|^2 + |fj|^2 - 2 fi.fj ; acc += 1/t^2
#define PAIR4(QX, QY, QZ, QP)                          \
    { _Pragma("unroll")                                \
      for (int u = 0; u < IPT; ++u) {                  \
        float t = si[u] + (QP);                        \
        t = fmaf(nx[u], (QX), t);                      \
        t = fmaf(ny[u], (QY), t);                      \
        t = fmaf(nz[u], (QZ), t);                      \
        float r = __builtin_amdgcn_rcpf(t);            \
        acc[u] = fmaf(r, r, acc[u]);                   \
      } }

// ---------------- Kernel 2: full-matrix rr-sum + bucket correction + reduce ----
__global__ __launch_bounds__(256) void mega_kernel(
    const float* __restrict__ fx, const float* __restrict__ fy,
    const float* __restrict__ fz, const float* __restrict__ fw,
    const int* __restrict__ target,
    double* __restrict__ partials, int* __restrict__ counter,
    float* __restrict__ out)
{
    const int bid = blockIdx.x;
    const int tid = threadIdx.x;

    __shared__ float4 sx[16], sy[16], sz[16], sp[16];
    __shared__ float4 pts[BUCK_CAP];
    __shared__ int    scnt[256];
    __shared__ int    sTotal;
    __shared__ double wsum[4];
    __shared__ int    elect;

    // ---------- pair phase (all 2048 blocks, perfectly uniform work) ----------
    const int b    = bid >> 10;
    const int rest = bid & 1023;
    const int it   = rest >> 7;
    const int jt   = rest & 127;
    const int base = b * NPTS;

    float nx[IPT], ny[IPT], nz[IPT], si[IPT];
    #pragma unroll
    for (int u = 0; u < IPT; ++u) {
        int i = base + it * ITILE + u * 256 + tid;
        nx[u] = -2.0f * fx[i];
        ny[u] = -2.0f * fy[i];
        nz[u] = -2.0f * fz[i];
        si[u] = fw[i] + 1.0f;
    }
    if (tid < 16) {
        int a = base + jt * JTILE + 4 * tid;
        sx[tid] = *(const float4*)&fx[a];
        sy[tid] = *(const float4*)&fy[a];
        sz[tid] = *(const float4*)&fz[a];
        sp[tid] = *(const float4*)&fw[a];
    }
    __syncthreads();

    float acc[IPT] = {0.f, 0.f, 0.f, 0.f};
    #pragma unroll 2
    for (int q = 0; q < 16; ++q) {
        float4 X = sx[q], Y = sy[q], Z = sz[q], P = sp[q];
        PAIR4(X.x, Y.x, Z.x, P.x)
        PAIR4(X.y, Y.y, Z.y, P.y)
        PAIR4(X.z, Y.z, Z.z, P.z)
        PAIR4(X.w, Y.w, Z.w, P.w)
    }
    float accPair = (acc[0] + acc[1]) + (acc[2] + acc[3]);

    // ---------- bucket phase (blocks 0..99): same-label pairs, (d - 2rr) ------
    float accB = 0.f;
    if (bid < NBUCKBLK) {
        const int bb    = bid / NGROUPS;
        const int L     = bid % NGROUPS;
        const int tbase = bb * NPTS;

        // count matches in this thread's contiguous 32-point segment
        int cnt = 0;
        const int4* t4 = (const int4*)&target[tbase];
        #pragma unroll
        for (int k8 = 0; k8 < 8; ++k8) {
            int4 tv = t4[tid * 8 + k8];
            cnt += (tv.x == L) + (tv.y == L) + (tv.z == L) + (tv.w == L);
        }
        scnt[tid] = cnt;
        __syncthreads();
        // Hillis-Steele inclusive scan over 256 counts (deterministic)
        for (int s = 1; s < 256; s <<= 1) {
            int addv = (tid >= s) ? scnt[tid - s] : 0;
            __syncthreads();
            scnt[tid] += addv;
            __syncthreads();
        }
        int off   = scnt[tid] - cnt;
        if (tid == 0) sTotal = min(scnt[255], BUCK_CAP);
        // stable scatter (by point index)
        int wpos = off;
        for (int k = 0; k < 32; ++k) {
            int idx = tid * 32 + k;
            if (target[tbase + idx] == L) {
                if (wpos < BUCK_CAP)
                    pts[wpos] = make_float4(fx[tbase + idx], fy[tbase + idx],
                                            fz[tbase + idx], 0.f);
                ++wpos;
            }
        }
        __syncthreads();
        const int total = sTotal;
        // sum (t - 2rr) over all ordered in-bucket pairs incl diag;
        // the (-1 per pair) and diag (+2 per point) corrections fold in later.
        for (int pp = tid; pp < total; pp += 256) {
            float4 a = pts[pp];
            for (int qq = 0; qq < total; ++qq) {
                float4 c = pts[qq];
                float dx = a.x - c.x, dy = a.y - c.y, dz = a.z - c.z;
                float t  = fmaf(dx, dx, fmaf(dy, dy, fmaf(dz, dz, 1.0f)));
                float r  = __builtin_amdgcn_rcpf(t);
                float rr = r * r;
                accB += fmaf(-2.0f, rr, t);
            }
        }
    }

    // ---------- combined block reduction ----------
    float myv = fmaf(accPair, 2.0f, accB);
    #pragma unroll
    for (int o = 32; o > 0; o >>= 1) myv += __shfl_down(myv, o, 64);
    if ((tid & 63) == 0) wsum[tid >> 6] = (double)myv;
    __syncthreads();
    if (tid == 0) {
        double blockSum = wsum[0] + wsum[1] + wsum[2] + wsum[3];
        if (bid < NBUCKBLK) {
            double T = (double)sTotal;
            blockSum += (-T * T + 2.0 * T);   // Σ(d-2rr) = Σ(t-2rr) - T²; +2T kills diag
        }
        partials[bid] = blockSum;
        __threadfence();
        int old = atomicAdd(counter, 1);
        elect = (old == NTOT - 1) ? 1 : 0;
    }
    __syncthreads();
    if (!elect) return;
    __threadfence();

    // elected (last) block: deterministic final reduction
    double s = 0.0;
    for (int k = tid; k < NTOT; k += 256) {
        unsigned long long uv = __hip_atomic_load(
            (unsigned long long*)&partials[k], __ATOMIC_RELAXED, __HIP_MEMORY_SCOPE_AGENT);
        s += __longlong_as_double(uv);
    }
    #pragma unroll
    for (int o = 32; o > 0; o >>= 1) s += __shfl_down(s, o, 64);
    __shared__ double sd[4];
    if ((tid & 63) == 0) sd[tid >> 6] = s;
    __syncthreads();
    if (tid == 0) {
        double tot = sd[0] + sd[1] + sd[2] + sd[3];
        // ref_total = 2*S1 - 2*B*N + bucket corrections (already folded)
        tot -= 2.0 * (double)(BATCH * NPTS);
        out[0] = (float)(100.0 * tot / ((double)BATCH * NPTS * NPTS));
    }
}

extern "C" void kernel_launch(void* const* d_in, const int* in_sizes, int n_in,
                              void* d_out, int out_size, void* d_ws, size_t ws_size,
                              hipStream_t stream) {
    const float* l0     = (const float*)d_in[0];   // [2,64,8192]
    const float* W      = (const float*)d_in[1];   // [3,64]
    const float* bias   = (const float*)d_in[2];   // [3]
    const int*   target = (const int*)d_in[3];     // [2,8192] (int32 on device)
    float* out = (float*)d_out;

    float* fx = (float*)d_ws;
    float* fy = fx + BATCH * NPTS;
    float* fz = fy + BATCH * NPTS;
    float* fw = fz + BATCH * NPTS;
    double* partials = (double*)((char*)d_ws + 4 * BATCH * NPTS * sizeof(float) + 256);
    int* counter = (int*)((char*)partials + NTOT * sizeof(double));

    fsim_kernel<<<BATCH * NPTS / 64, 256, 0, stream>>>(l0, W, bias, fx, fy, fz, fw, counter);
    mega_kernel<<<NTOT, 256, 0, stream>>>(fx, fy, fz, fw, target, partials, counter, out);
}